// Round 6
// baseline (208.998 us; speedup 1.0000x reference)
//
#include <hip/hip_runtime.h>
#include <hip/hip_cooperative_groups.h>

namespace cg = cooperative_groups;

#define D 32
#define T 2049
#define NH 2
#define NBLK 257   // 257 * 8 = 2056 >= 2049 columns

// ---------------------------------------------------------------------------
// One cooperative kernel does the whole 2-layer forward:
//   [phase S layer0] sig(U=B@Z, W=C@Z)  -> grid.sync
//   [phase A layer0] Zmid = Z + attn    -> grid.sync
//   [phase S layer1] sigs from Zmid     -> grid.sync
//   [phase A layer1] out  = Zmid + attn
// attn[l,j] = 1 iff 32-bit sign signature of U[:,l] == signature of W[:,j]
// (bit k = u[k]>0, bit 32 = any zero -> never matches / kills column).
// Expected matches ~ 2*2049^2/2^32 ~ 0.002 -> rare path recomputes V@Z[:,l].
// ---------------------------------------------------------------------------
__global__ __launch_bounds__(256) void fused_kernel(
    const float* __restrict__ Z0,        // (32, 2049)
    const float* __restrict__ allparam,  // (2,2,3,32,32)
    float* __restrict__ Zmid,            // ws: (32, 2049)
    unsigned long long* __restrict__ sigU, // ws: (NH, T)
    unsigned long long* __restrict__ sigW, // ws: (NH, T)
    float* __restrict__ out)             // (32, 2049)
{
    cg::grid_group grid = cg::this_grid();
    const int tid = threadIdx.x;
    const int b   = blockIdx.x;

    __shared__ float Bs[NH][32][32];
    __shared__ float Cs[NH][32][32];
    __shared__ float Zs[32][8];

    for (int layer = 0; layer < 2; ++layer) {
        const float* Zin = layer ? Zmid : Z0;
        float*       Zout = layer ? out : Zmid;
        const float* pbase = allparam + (size_t)layer * NH * 3 * 1024;

        // ---------------- phase S: signatures for this block's 8 columns ----
        {
            #pragma unroll
            for (int h = 0; h < NH; ++h) {
                const float* Bp = pbase + (h * 3 + 1) * 1024;
                const float* Cp = pbase + (h * 3 + 2) * 1024;
                #pragma unroll
                for (int i = 0; i < 4; ++i) {
                    ((float*)Bs[h])[tid + 256 * i] = Bp[tid + 256 * i];
                    ((float*)Cs[h])[tid + 256 * i] = Cp[tid + 256 * i];
                }
            }
            {
                int d = tid >> 3, c = tid & 7;
                int t = b * 8 + c; if (t >= T) t = T - 1;  // clamp, keep lanes live
                Zs[d][c] = Zin[d * T + t];
            }
            __syncthreads();

            const int c = tid >> 5;     // column in group (0..7)
            const int k = tid & 31;     // row
            const int t = b * 8 + c;
            #pragma unroll
            for (int h = 0; h < NH; ++h) {
                float u = 0.f, w = 0.f;
                #pragma unroll
                for (int d = 0; d < 32; ++d) {
                    float z = Zs[d][c];
                    u += Bs[h][k][d] * z;
                    w += Cs[h][k][d] * z;
                }
                unsigned long long pu = __ballot(u > 0.0f);
                unsigned long long zu = __ballot(u == 0.0f);
                unsigned long long pw = __ballot(w > 0.0f);
                unsigned long long zw = __ballot(w == 0.0f);
                const int wid = tid & 63;
                if ((wid == 0 || wid == 32) && t < T) {
                    const int sh = (wid == 0) ? 0 : 32;
                    unsigned long long su = (unsigned int)(pu >> sh);
                    if ((unsigned int)(zu >> sh)) su |= (1ull << 32);
                    unsigned long long sw = (unsigned int)(pw >> sh);
                    if ((unsigned int)(zw >> sh)) sw |= (1ull << 32);
                    sigU[h * T + t] = su;
                    sigW[h * T + t] = sw;
                }
            }
        }
        grid.sync();   // sigs visible device-wide

        // ---------------- phase A: 2 output columns per wave ----------------
        {
            const int widx = tid >> 6;        // 0..3
            const int lane = tid & 63;
            const int k    = lane & 31;
            const int j0   = b * 8 + widx * 2;
            const int j1   = j0 + 1;
            float acc0 = 0.f, acc1 = 0.f;

            #pragma unroll
            for (int h = 0; h < NH; ++h) {
                unsigned long long wv0 = (j0 < T) ? sigW[h * T + j0] : ~0ull;
                unsigned long long wv1 = (j1 < T) ? sigW[h * T + j1] : ~0ull;
                const bool s0 = (wv0 >> 32) != 0;   // zero-flag -> column dead
                const bool s1 = (wv1 >> 32) != 0;
                if (s0 && s1) continue;             // wave-uniform
                const float* V = pbase + h * 3 * 1024;   // channel 0
                const unsigned long long* su = sigU + h * T;
                for (int it = 0; it < 32; ++it) {   // 32*64 = 2048 = T-1 sources
                    const int l = it * 64 + lane;
                    const unsigned long long sv = su[l];
                    unsigned long long m0 = __ballot(!s0 && sv == wv0);
                    unsigned long long m1 = __ballot(!s1 && sv == wv1);
                    while (m0) {                    // rare path
                        const int bb = __builtin_ctzll(m0); m0 &= m0 - 1;
                        const int lm = it * 64 + bb;
                        float kv = 0.f;
                        #pragma unroll
                        for (int d = 0; d < 32; ++d)
                            kv += V[k * 32 + d] * Zin[d * T + lm];
                        acc0 += kv;
                    }
                    while (m1) {
                        const int bb = __builtin_ctzll(m1); m1 &= m1 - 1;
                        const int lm = it * 64 + bb;
                        float kv = 0.f;
                        #pragma unroll
                        for (int d = 0; d < 32; ++d)
                            kv += V[k * 32 + d] * Zin[d * T + lm];
                        acc1 += kv;
                    }
                }
            }
            if (lane < 32) {
                if (j0 < T) Zout[k * T + j0] = Zin[k * T + j0] + acc0;
                if (j1 < T) Zout[k * T + j1] = Zin[k * T + j1] + acc1;
            }
        }
        if (layer == 0) grid.sync();   // Zmid complete before layer 1
    }
}

extern "C" void kernel_launch(void* const* d_in, const int* in_sizes, int n_in,
                              void* d_out, int out_size, void* d_ws, size_t ws_size,
                              hipStream_t stream) {
    const float* Z        = (const float*)d_in[0];   // (32, 2049) f32
    const float* allparam = (const float*)d_in[1];   // (2,2,3,32,32) f32
    float* out            = (float*)d_out;

    // workspace layout
    float* Zmid = (float*)d_ws;                                   // 32*2049 f32
    size_t sig_off = ((size_t)D * T * sizeof(float) + 255) & ~(size_t)255;
    unsigned long long* sigU = (unsigned long long*)((char*)d_ws + sig_off);
    unsigned long long* sigW = sigU + (size_t)NH * T;

    void* args[] = { (void*)&Z, (void*)&allparam, (void*)&Zmid,
                     (void*)&sigU, (void*)&sigW, (void*)&out };
    hipLaunchCooperativeKernel((const void*)fused_kernel,
                               dim3(NBLK), dim3(256), args, 0, stream);
}

// Round 7
// 75.323 us; speedup vs baseline: 2.7747x; 2.7747x over previous
//
#include <hip/hip_runtime.h>

#define D 32
#define T 2049
#define NH 2
#define NBLK 257          // 257 * 8 = 2056 >= 2049 columns
#define PAD 33            // LDS row pad: (k*33+d)%32 hits distinct banks

typedef unsigned long long u64;

// ---------------------------------------------------------------------------
// Exact-sign-signature formulation (verified R3, absmax 0.0):
// attn[l,j] = 1 iff 32-bit sign signature of (B@Z)[:,l] equals that of
// (C@Z)[:,j]; bit k = x[k] > 0, bit 32 = any exact zero (never matches /
// kills the column). Expected matches ~ 2*2049^2/2^32 ~ 0.002 -> output is
// the residual passthrough; rare path recomputes V@Z[:,l] exactly on match.
//
// Pipeline (3 kernels, plain launches — grid.sync measured slower, R6):
//   K1 sig0:      sigs of layer 0 from Z
//   K2 attn+sig1: Zmid = Z + attn0; layer-1 sigs from in-register Zmid
//   K3 attn:      out  = Zmid + attn1
// ---------------------------------------------------------------------------

__device__ __forceinline__ void sig_from_lds(
    const float (*Bs)[32][PAD], const float (*Cs)[32][PAD],
    const float* Zcol,           // LDS column (32 floats, broadcast reads)
    int tid, int t,
    u64* __restrict__ sigU, u64* __restrict__ sigW)
{
    const int k = tid & 31;
    #pragma unroll
    for (int h = 0; h < NH; ++h) {
        float u = 0.f, w = 0.f;
        #pragma unroll
        for (int d = 0; d < 32; ++d) {
            float z = Zcol[d];
            u += Bs[h][k][d] * z;
            w += Cs[h][k][d] * z;
        }
        u64 pu = __ballot(u > 0.0f);
        u64 zu = __ballot(u == 0.0f);
        u64 pw = __ballot(w > 0.0f);
        u64 zw = __ballot(w == 0.0f);
        const int wid = tid & 63;
        if ((wid == 0 || wid == 32) && t < T) {
            const int sh = (wid == 0) ? 0 : 32;
            u64 su = (unsigned int)(pu >> sh);
            if ((unsigned int)(zu >> sh)) su |= (1ull << 32);
            u64 sw = (unsigned int)(pw >> sh);
            if ((unsigned int)(zw >> sh)) sw |= (1ull << 32);
            sigU[h * T + t] = su;
            sigW[h * T + t] = sw;
        }
    }
}

// ---------------- K1: layer-0 signatures ------------------------------------
__global__ __launch_bounds__(256) void sig0_kernel(
    const float* __restrict__ Z, const float* __restrict__ allparam,
    u64* __restrict__ sigU, u64* __restrict__ sigW)
{
    const int tid = threadIdx.x, b = blockIdx.x;
    __shared__ float Bs[NH][32][PAD];
    __shared__ float Cs[NH][32][PAD];
    __shared__ float Zs[8][32];

    #pragma unroll
    for (int h = 0; h < NH; ++h) {
        const float* Bp = allparam + (h * 3 + 1) * 1024;
        const float* Cp = allparam + (h * 3 + 2) * 1024;
        #pragma unroll
        for (int i = 0; i < 4; ++i) {
            int idx = tid + 256 * i;
            Bs[h][idx >> 5][idx & 31] = Bp[idx];
            Cs[h][idx >> 5][idx & 31] = Cp[idx];
        }
    }
    {
        int d = tid >> 3, c = tid & 7;
        int t = b * 8 + c; if (t >= T) t = T - 1;
        Zs[c][d] = Z[d * T + t];
    }
    __syncthreads();

    const int c = tid >> 5;
    sig_from_lds(Bs, Cs, Zs[c], tid, b * 8 + c, sigU, sigW);
}

// ---------------- attn scan for one wave's two columns ----------------------
__device__ __forceinline__ void attn_scan(
    const float* __restrict__ Zin, const float* __restrict__ pbase,
    const u64* __restrict__ sigU, const u64* __restrict__ sigW,
    int j0, int j1, int lane, int k, float& acc0, float& acc1)
{
    #pragma unroll
    for (int h = 0; h < NH; ++h) {
        u64 wv0 = (j0 < T) ? sigW[h * T + j0] : ~0ull;
        u64 wv1 = (j1 < T) ? sigW[h * T + j1] : ~0ull;
        const bool s0 = (wv0 >> 32) != 0;   // zero-flag -> dead column
        const bool s1 = (wv1 >> 32) != 0;
        if (s0 && s1) continue;             // wave-uniform
        const float* V = pbase + h * 3 * 1024;
        const u64* su = sigU + h * T;
        for (int it0 = 0; it0 < 32; it0 += 8) {   // 32*64 = 2048 = T-1 sources
            u64 sv[8];
            #pragma unroll
            for (int q = 0; q < 8; ++q)           // prefetch: 1 wait per 8 loads
                sv[q] = su[(it0 + q) * 64 + lane];
            #pragma unroll
            for (int q = 0; q < 8; ++q) {
                u64 m0 = __ballot(!s0 && sv[q] == wv0);
                u64 m1 = __ballot(!s1 && sv[q] == wv1);
                while (m0) {                      // rare exact path
                    const int bb = __builtin_ctzll(m0); m0 &= m0 - 1;
                    const int lm = (it0 + q) * 64 + bb;
                    float kv = 0.f;
                    #pragma unroll
                    for (int d = 0; d < 32; ++d)
                        kv += V[k * 32 + d] * Zin[d * T + lm];
                    acc0 += kv;
                }
                while (m1) {
                    const int bb = __builtin_ctzll(m1); m1 &= m1 - 1;
                    const int lm = (it0 + q) * 64 + bb;
                    float kv = 0.f;
                    #pragma unroll
                    for (int d = 0; d < 32; ++d)
                        kv += V[k * 32 + d] * Zin[d * T + lm];
                    acc1 += kv;
                }
            }
        }
    }
}

// ---------------- K2: attn layer 0 + signatures layer 1 ---------------------
__global__ __launch_bounds__(256) void attn_sig_kernel(
    const float* __restrict__ Zin, const float* __restrict__ allparam,
    const u64* __restrict__ sig0U, const u64* __restrict__ sig0W,
    u64* __restrict__ sig1U, u64* __restrict__ sig1W,
    float* __restrict__ Zout)
{
    const int tid = threadIdx.x, b = blockIdx.x;
    const int w = tid >> 6, lane = tid & 63, k = lane & 31, half = lane >> 5;
    const int j0 = b * 8 + w * 2, j1 = j0 + 1;

    __shared__ float Bs[NH][32][PAD];   // layer-1 B
    __shared__ float Cs[NH][32][PAD];   // layer-1 C
    __shared__ float Zs[8][32];         // fresh Zmid columns

    // stage layer-1 B,C (overlaps with attn below; waits resolved at barrier)
    const float* p1 = allparam + NH * 3 * 1024;
    #pragma unroll
    for (int h = 0; h < NH; ++h) {
        const float* Bp = p1 + (h * 3 + 1) * 1024;
        const float* Cp = p1 + (h * 3 + 2) * 1024;
        #pragma unroll
        for (int i = 0; i < 4; ++i) {
            int idx = tid + 256 * i;
            Bs[h][idx >> 5][idx & 31] = Bp[idx];
            Cs[h][idx >> 5][idx & 31] = Cp[idx];
        }
    }

    // attn layer 0 for columns j0, j1
    float acc0 = 0.f, acc1 = 0.f;
    attn_scan(Zin, allparam, sig0U, sig0W, j0, j1, lane, k, acc0, acc1);

    // residual add, write Zmid, stage fresh column into LDS
    const int jc   = half ? j1 : j0;
    const float ac = half ? acc1 : acc0;
    float r = 0.f;
    if (jc < T) {
        r = Zin[k * T + jc] + ac;
        Zout[k * T + jc] = r;
    }
    Zs[w * 2 + half][k] = r;
    __syncthreads();

    // layer-1 signatures from in-register/LDS Zmid columns
    const int c = tid >> 5;   // == w*2 + half
    sig_from_lds(Bs, Cs, Zs[c], tid, b * 8 + c, sig1U, sig1W);
}

// ---------------- K3: attn layer 1 ------------------------------------------
__global__ __launch_bounds__(256) void attn_kernel(
    const float* __restrict__ Zin, const float* __restrict__ allparam,
    const u64* __restrict__ sigU, const u64* __restrict__ sigW,
    float* __restrict__ Zout)
{
    const int tid = threadIdx.x, b = blockIdx.x;
    const int w = tid >> 6, lane = tid & 63, k = lane & 31, half = lane >> 5;
    const int j0 = b * 8 + w * 2, j1 = j0 + 1;
    const float* p1 = allparam + NH * 3 * 1024;   // layer 1 params

    float acc0 = 0.f, acc1 = 0.f;
    attn_scan(Zin, p1, sigU, sigW, j0, j1, lane, k, acc0, acc1);

    const int jc   = half ? j1 : j0;
    const float ac = half ? acc1 : acc0;
    if (jc < T) Zout[k * T + jc] = Zin[k * T + jc] + ac;
}

extern "C" void kernel_launch(void* const* d_in, const int* in_sizes, int n_in,
                              void* d_out, int out_size, void* d_ws, size_t ws_size,
                              hipStream_t stream) {
    const float* Z        = (const float*)d_in[0];   // (32, 2049) f32
    const float* allparam = (const float*)d_in[1];   // (2,2,3,32,32) f32
    float* out            = (float*)d_out;

    // workspace layout
    float* Zmid = (float*)d_ws;                                    // 32*2049 f32
    size_t off = ((size_t)D * T * sizeof(float) + 255) & ~(size_t)255;
    u64* sig0U = (u64*)((char*)d_ws + off);
    u64* sig0W = sig0U + (size_t)NH * T;
    u64* sig1U = sig0W + (size_t)NH * T;
    u64* sig1W = sig1U + (size_t)NH * T;

    sig0_kernel<<<NBLK, 256, 0, stream>>>(Z, allparam, sig0U, sig0W);
    attn_sig_kernel<<<NBLK, 256, 0, stream>>>(Z, allparam, sig0U, sig0W,
                                              sig1U, sig1W, Zmid);
    attn_kernel<<<NBLK, 256, 0, stream>>>(Zmid, allparam, sig1U, sig1W, out);
}